// Round 2
// baseline (678.592 us; speedup 1.0000x reference)
//
#include <hip/hip_runtime.h>
#include <hip/hip_bf16.h>

#define B_ 4
#define L_ 3136
#define D_ 256
#define NCH 49     // 49 chunks * 64 = 3136
#define LCH 64
#define M_ (B_*L_)

__device__ __forceinline__ float bf2f(unsigned short u) {
    union { unsigned int i; float f; } v; v.i = ((unsigned int)u) << 16; return v.f;
}
__device__ __forceinline__ unsigned short f2bs(float f) {
    __hip_bfloat16 h = __float2bfloat16(f);
    return *(unsigned short*)&h;
}
// dual-dtype load for INPUT tensors (bf16 if flag, else fp32)
__device__ __forceinline__ float ldw(const void* p, size_t i, bool bf) {
    return bf ? bf2f(((const unsigned short*)p)[i]) : ((const float*)p)[i];
}

// ------------------------------------------------- dtype detection
// Examine low ushort of first 2048 u32 words of x. If x is bf16: those are
// real bf16 elements of N(0,1) data -> exponent in sane window ~100%.
// If x is fp32: those are random mantissa bits -> ~25% in window.
__global__ __launch_bounds__(256) void detect_kernel(
    const unsigned int* __restrict__ xw, int* __restrict__ flag)
{
    int t = threadIdx.x; int cnt = 0;
    for (int i = t; i < 2048; i += 256) {
        unsigned int lo = xw[i] & 0xFFFFu;
        unsigned int e = (lo >> 7) & 0xFFu;
        if (e >= 0x58u && e <= 0x97u) cnt++;
    }
    #pragma unroll
    for (int o = 32; o > 0; o >>= 1) cnt += __shfl_down(cnt, o);
    __shared__ int sred[4];
    if ((t & 63) == 0) sred[t >> 6] = cnt;
    __syncthreads();
    if (t == 0) flag[0] = (sred[0] + sred[1] + sred[2] + sred[3] > 1024) ? 1 : 0;
}

// ------------------------------------------------- LayerNorm -> bf16 out
__global__ __launch_bounds__(256) void ln_kernel(
    const void* __restrict__ xin, int inmode,   // -1: dual via flag; 1: bf16
    const void* __restrict__ g, const void* __restrict__ bsh,
    unsigned short* __restrict__ out, const int* __restrict__ flagp)
{
    const bool wbf = (*flagp != 0);
    const bool inbf = (inmode < 0) ? wbf : true;
    int row = blockIdx.x, t = threadIdx.x;
    size_t idx = (size_t)row * 256 + t;
    float v = inbf ? bf2f(((const unsigned short*)xin)[idx]) : ((const float*)xin)[idx];
    float s = v, s2 = v * v;
    #pragma unroll
    for (int o = 32; o > 0; o >>= 1) { s += __shfl_down(s, o); s2 += __shfl_down(s2, o); }
    __shared__ float red[8];
    int w = t >> 6;
    if ((t & 63) == 0) { red[w] = s; red[4 + w] = s2; }
    __syncthreads();
    float S  = red[0] + red[1] + red[2] + red[3];
    float S2 = red[4] + red[5] + red[6] + red[7];
    float mean = S * (1.f / 256.f);
    float var  = S2 * (1.f / 256.f) - mean * mean;
    float rs = rsqrtf(var + 1e-5f);
    out[idx] = f2bs((v - mean) * rs * ldw(g, t, wbf) + ldw(bsh, t, wbf));
}

// ------------------------------------------------- GEMM
// C[M,N] = A[M,K] * W[N,K]^T.  A: bf16 (ABF) or fp32; optional split A source
// at k==Ksplit (for concat(y,z)).  W/bias/res: dual-dtype input tensors.
enum { EPI_NONE = 0, EPI_SP = 1, EPI_RES = 2, EPI_GELU = 3, EPI_OUT = 4 };

template<int EPI, bool ABF, bool CBF>
__global__ __launch_bounds__(256) void gemm_kernel(
    const void* __restrict__ A, const void* __restrict__ A2, int Ksplit,
    const void* __restrict__ W, void* __restrict__ Cout,
    int N, int K, int lda, int ldc,
    const void* __restrict__ bias, const void* __restrict__ resb,
    const unsigned short* __restrict__ resf, const int* __restrict__ flagp)
{
    const bool wbf = (*flagp != 0);
    __shared__ float As[16][132];
    __shared__ float Ws[16][132];
    const int tid = threadIdx.x;
    const int bm = blockIdx.y * 128, bn = blockIdx.x * 128;
    const int tx = tid & 15, ty = tid >> 4;
    const int lrow = tid >> 1;
    const int lk = (tid & 1) * 8;

    float acc[8][8];
    #pragma unroll
    for (int i = 0; i < 8; ++i)
        #pragma unroll
        for (int j = 0; j < 8; ++j) acc[i][j] = 0.f;

    for (int k0 = 0; k0 < K; k0 += 16) {
        float av[8];
        if (ABF) {
            const unsigned short* Ab; int kc;
            if (k0 < Ksplit) { Ab = (const unsigned short*)A;  kc = k0; }
            else             { Ab = (const unsigned short*)A2; kc = k0 - Ksplit; }
            const unsigned short* Ap = Ab + (size_t)(bm + lrow) * lda + kc + lk;
            ushort4 a0 = *(const ushort4*)Ap;
            ushort4 a1 = *(const ushort4*)(Ap + 4);
            av[0] = bf2f(a0.x); av[1] = bf2f(a0.y); av[2] = bf2f(a0.z); av[3] = bf2f(a0.w);
            av[4] = bf2f(a1.x); av[5] = bf2f(a1.y); av[6] = bf2f(a1.z); av[7] = bf2f(a1.w);
        } else {
            const float* Ap = (const float*)A + (size_t)(bm + lrow) * lda + k0 + lk;
            float4 a0 = *(const float4*)Ap;
            float4 a1 = *(const float4*)(Ap + 4);
            av[0] = a0.x; av[1] = a0.y; av[2] = a0.z; av[3] = a0.w;
            av[4] = a1.x; av[5] = a1.y; av[6] = a1.z; av[7] = a1.w;
        }
        #pragma unroll
        for (int j = 0; j < 8; ++j) As[lk + j][lrow] = av[j];

        int n = bn + lrow;
        float wv[8];
        #pragma unroll
        for (int j = 0; j < 8; ++j) wv[j] = 0.f;
        if (n < N) {
            if (wbf) {
                const unsigned short* Wp = (const unsigned short*)W + (size_t)n * K + k0 + lk;
                ushort4 w0 = *(const ushort4*)Wp;
                ushort4 w1 = *(const ushort4*)(Wp + 4);
                wv[0] = bf2f(w0.x); wv[1] = bf2f(w0.y); wv[2] = bf2f(w0.z); wv[3] = bf2f(w0.w);
                wv[4] = bf2f(w1.x); wv[5] = bf2f(w1.y); wv[6] = bf2f(w1.z); wv[7] = bf2f(w1.w);
            } else {
                const float* Wp = (const float*)W + (size_t)n * K + k0 + lk;
                float4 w0 = *(const float4*)Wp;
                float4 w1 = *(const float4*)(Wp + 4);
                wv[0] = w0.x; wv[1] = w0.y; wv[2] = w0.z; wv[3] = w0.w;
                wv[4] = w1.x; wv[5] = w1.y; wv[6] = w1.z; wv[7] = w1.w;
            }
        }
        #pragma unroll
        for (int j = 0; j < 8; ++j) Ws[lk + j][lrow] = wv[j];
        __syncthreads();

        #pragma unroll
        for (int k = 0; k < 16; ++k) {
            float a[8], b[8];
            *(float4*)&a[0] = *(const float4*)&As[k][ty * 8];
            *(float4*)&a[4] = *(const float4*)&As[k][ty * 8 + 4];
            *(float4*)&b[0] = *(const float4*)&Ws[k][tx * 8];
            *(float4*)&b[4] = *(const float4*)&Ws[k][tx * 8 + 4];
            #pragma unroll
            for (int i = 0; i < 8; ++i)
                #pragma unroll
                for (int j = 0; j < 8; ++j)
                    acc[i][j] = fmaf(a[i], b[j], acc[i][j]);
        }
        __syncthreads();
    }

    #pragma unroll
    for (int i = 0; i < 8; ++i) {
        int m = bm + ty * 8 + i;
        #pragma unroll
        for (int jq = 0; jq < 2; ++jq) {
            int ncol = bn + tx * 8 + jq * 4;
            if (ncol < N) {
                float v[4];
                #pragma unroll
                for (int j = 0; j < 4; ++j) {
                    float t = acc[i][jq * 4 + j];
                    int n = ncol + j;
                    if (EPI == EPI_SP) {
                        t += ldw(bias, n, wbf);
                        t = (t > 20.f) ? t : log1pf(__expf(t));
                    } else if (EPI == EPI_RES) {
                        t += ldw(resb, (size_t)m * 256 + n, wbf);
                    } else if (EPI == EPI_GELU) {
                        t += ldw(bias, n, wbf);
                        t = 0.5f * t * (1.f + erff(t * 0.70710678118654752f));
                    } else if (EPI == EPI_OUT) {
                        t += ldw(bias, n, wbf) + bf2f(resf[(size_t)m * 256 + n]);
                    }
                    v[j] = t;
                }
                if (EPI == EPI_OUT) {
                    if (wbf) {
                        ushort4 o;
                        o.x = f2bs(v[0]); o.y = f2bs(v[1]); o.z = f2bs(v[2]); o.w = f2bs(v[3]);
                        *(ushort4*)((unsigned short*)Cout + (size_t)m * ldc + ncol) = o;
                    } else {
                        *(float4*)((float*)Cout + (size_t)m * ldc + ncol) = *(float4*)v;
                    }
                } else if (CBF) {
                    ushort4 o;
                    o.x = f2bs(v[0]); o.y = f2bs(v[1]); o.z = f2bs(v[2]); o.w = f2bs(v[3]);
                    *(ushort4*)((unsigned short*)Cout + (size_t)m * ldc + ncol) = o;
                } else {
                    *(float4*)((float*)Cout + (size_t)m * ldc + ncol) = *(float4*)v;
                }
            }
        }
    }
}

// ------------------------------------------------- depthwise conv3 + SiLU
__global__ __launch_bounds__(256) void conv_silu_kernel(
    const unsigned short* __restrict__ xz,
    const void* __restrict__ wx, const void* __restrict__ wz,
    unsigned short* __restrict__ u, unsigned short* __restrict__ z,
    const int* __restrict__ flagp)
{
    const bool wbf = (*flagp != 0);
    int bl = blockIdx.x, t = threadIdx.x;
    int l = bl % L_;
    const unsigned short* r = xz + (size_t)bl * 512;
    bool hasm = (l > 0), hasp = (l < L_ - 1);

    float xm = hasm ? bf2f(r[(int)t - 512]) : 0.f;
    float xc = bf2f(r[t]);
    float xp = hasp ? bf2f(r[t + 512]) : 0.f;
    float v = xm * ldw(wx, 3 * t, wbf) + xc * ldw(wx, 3 * t + 1, wbf) + xp * ldw(wx, 3 * t + 2, wbf);
    v = v / (1.f + __expf(-v));
    u[(size_t)bl * 256 + t] = f2bs(v);

    float zm = hasm ? bf2f(r[(int)t - 256]) : 0.f;   // prev token, channel 256+t
    float zc = bf2f(r[256 + t]);
    float zp = hasp ? bf2f(r[768 + t]) : 0.f;
    float vz = zm * ldw(wz, 3 * t, wbf) + zc * ldw(wz, 3 * t + 1, wbf) + zp * ldw(wz, 3 * t + 2, wbf);
    vz = vz / (1.f + __expf(-vz));
    z[(size_t)bl * 256 + t] = f2bs(vz);
}

// ------------------------------------------------- selective scan (chunked)
__global__ __launch_bounds__(256) void scan_a_kernel(
    const unsigned short* __restrict__ delta, const unsigned short* __restrict__ u,
    const float* __restrict__ xdbl, const void* __restrict__ A_log,
    float* __restrict__ hend, float* __restrict__ dsum, const int* __restrict__ flagp)
{
    const bool wbf = (*flagp != 0);
    int blk = blockIdx.x;
    int b = blk / (NCH * 16);
    int rem = blk % (NCH * 16);
    int c = rem / 16, db = rem % 16;
    int g = threadIdx.x >> 4, n = threadIdx.x & 15;
    int d = db * 16 + g;

    float An = -__expf(ldw(A_log, d * 16 + n, wbf));
    float h = 0.f, s = 0.f;
    const unsigned short* dp = delta + (size_t)b * L_ * 256;
    const unsigned short* up = u     + (size_t)b * L_ * 256;
    const float* xd = xdbl + (size_t)b * L_ * 48;
    int lbase = c * LCH;
    for (int t2 = 0; t2 < LCH; ++t2) {
        int l = lbase + t2;
        float ds = bf2f(dp[(size_t)l * 256 + d]);
        float ut = bf2f(up[(size_t)l * 256 + d]);
        float Bn = xd[(size_t)l * 48 + 16 + n];
        h = __expf(ds * An) * h + ds * Bn * ut;
        s += ds;
    }
    size_t pair = (size_t)b * 256 + d;
    hend[(pair * NCH + c) * 16 + n] = h;
    if (n == 0) dsum[pair * NCH + c] = s;
}

// combine across chunks; overwrite hend with per-chunk INITIAL states (in place)
__global__ __launch_bounds__(256) void scan_b_kernel(
    const void* __restrict__ A_log, float* __restrict__ hend,
    const float* __restrict__ dsum, const int* __restrict__ flagp)
{
    const bool wbf = (*flagp != 0);
    int gid = blockIdx.x * 256 + threadIdx.x;   // 16384
    int pair = gid >> 4, n = gid & 15;
    int d = pair & 255;
    float An = -__expf(ldw(A_log, d * 16 + n, wbf));
    float H = 0.f;
    for (int c = 0; c < NCH; ++c) {
        size_t idx = ((size_t)pair * NCH + c) * 16 + n;
        float he = hend[idx];
        hend[idx] = H;
        H = __expf(An * dsum[(size_t)pair * NCH + c]) * H + he;
    }
}

__global__ __launch_bounds__(256) void scan_c_kernel(
    const unsigned short* __restrict__ delta, const unsigned short* __restrict__ u,
    const float* __restrict__ xdbl, const void* __restrict__ A_log,
    const void* __restrict__ Dp, const float* __restrict__ hinit,
    unsigned short* __restrict__ y, const int* __restrict__ flagp)
{
    const bool wbf = (*flagp != 0);
    int blk = blockIdx.x;
    int b = blk / (NCH * 16);
    int rem = blk % (NCH * 16);
    int c = rem / 16, db = rem % 16;
    int g = threadIdx.x >> 4, n = threadIdx.x & 15;
    int d = db * 16 + g;

    float An = -__expf(ldw(A_log, d * 16 + n, wbf));
    float Dd = ldw(Dp, d, wbf);
    size_t pair = (size_t)b * 256 + d;
    float h = hinit[(pair * NCH + c) * 16 + n];
    const unsigned short* dp = delta + (size_t)b * L_ * 256;
    const unsigned short* up = u     + (size_t)b * L_ * 256;
    const float* xd = xdbl + (size_t)b * L_ * 48;
    int lbase = c * LCH;
    for (int t2 = 0; t2 < LCH; ++t2) {
        int l = lbase + t2;
        float ds = bf2f(dp[(size_t)l * 256 + d]);
        float ut = bf2f(up[(size_t)l * 256 + d]);
        float Bn = xd[(size_t)l * 48 + 16 + n];
        float Cn = xd[(size_t)l * 48 + 32 + n];
        h = __expf(ds * An) * h + ds * Bn * ut;
        float yp = h * Cn;
        yp += __shfl_xor(yp, 1);
        yp += __shfl_xor(yp, 2);
        yp += __shfl_xor(yp, 4);
        yp += __shfl_xor(yp, 8);
        if (n == 0)
            y[((size_t)b * L_ + l) * 256 + d] = f2bs(yp + ut * Dd);
    }
}

// ------------------------------------------------- launch
extern "C" void kernel_launch(void* const* d_in, const int* in_sizes, int n_in,
                              void* d_out, int out_size, void* d_ws, size_t ws_size,
                              hipStream_t stream) {
    const void* x         = d_in[0];
    const void* ln1_g     = d_in[1];
    const void* ln1_b     = d_in[2];
    const void* ln2_g     = d_in[3];
    const void* ln2_b     = d_in[4];
    const void* in_proj_w = d_in[5];
    const void* conv_x_w  = d_in[6];
    const void* conv_z_w  = d_in[7];
    const void* x_proj_w  = d_in[8];
    const void* dt_proj_w = d_in[9];
    const void* dt_proj_b = d_in[10];
    const void* A_log     = d_in[11];
    const void* Dp        = d_in[12];
    const void* out_proj_w= d_in[13];
    const void* mlp_w1    = d_in[14];
    const void* mlp_b1    = d_in[15];
    const void* mlp_w2    = d_in[16];
    const void* mlp_b2    = d_in[17];

    // Workspace layout (units: fp32 words). Total = 9,633,793 words = 36.7 MB.
    // R0 [0,3211264): xz(bf16, steps 2-3) -> delta(bf16, lower half) + y(bf16, upper half)
    // R3 [3211264,3813376): xdbl fp32
    // R4 [3813376,4666368): hend(3211264..) wait -- hend + dsum (scan, fp32)
    // EXT[4666368,6422528): only used by hmid
    // hmid(bf16) = [0,6422528) overlays R0|R3|R4|EXT (all dead by MLP time)
    // R1 [6422528,8028160): u(bf16) -> xres(bf16)
    // R2 [8028160,9633792): xn(bf16) -> z(bf16) -> xn2(bf16)
    // flag at word 9633792
    float* ws = (float*)d_ws;
    unsigned short* xz    = (unsigned short*)(ws);
    unsigned short* delta = (unsigned short*)(ws);
    unsigned short* yb    = (unsigned short*)(ws + 1605632);
    float*          xdbl  = ws + 3211264;
    float*          hend  = ws + 3813376;
    float*          dsum  = ws + 4616192;
    unsigned short* hmid  = (unsigned short*)(ws);
    unsigned short* ub    = (unsigned short*)(ws + 6422528);
    unsigned short* xres  = (unsigned short*)(ws + 6422528);  // alias of ub (u dead)
    unsigned short* xnb   = (unsigned short*)(ws + 8028160);  // xn / z / xn2
    int*            flag  = (int*)(ws + 9633792);

    dim3 blk(256);

    // 0. dtype detection -> flag
    detect_kernel<<<1, blk, 0, stream>>>((const unsigned int*)x, flag);

    // 1. LN1: x(dual) -> xn (bf16)
    ln_kernel<<<M_, blk, 0, stream>>>(x, -1, ln1_g, ln1_b, xnb, flag);

    // 2. in_proj: xn (M,256) x W(512,256)^T -> xz (M,512) bf16
    gemm_kernel<EPI_NONE, true, true><<<dim3(4, 98), blk, 0, stream>>>(
        xnb, nullptr, 256, in_proj_w, xz, 512, 256, 256, 512, nullptr, nullptr, nullptr, flag);

    // 3. conv+silu: xz -> u (bf16), z (bf16, overwrites xn)
    conv_silu_kernel<<<M_, blk, 0, stream>>>(xz, conv_x_w, conv_z_w, ub, xnb, flag);

    // 4. x_proj: u (M,256) x W(48,256)^T -> xdbl (M,48) fp32
    gemm_kernel<EPI_NONE, true, false><<<dim3(1, 98), blk, 0, stream>>>(
        ub, nullptr, 256, x_proj_w, xdbl, 48, 256, 256, 48, nullptr, nullptr, nullptr, flag);

    // 5. dt_proj + softplus: xdbl[:,:16] x W(256,16)^T -> delta (bf16, overwrites xz lower)
    gemm_kernel<EPI_SP, false, true><<<dim3(2, 98), blk, 0, stream>>>(
        xdbl, nullptr, 16, dt_proj_w, delta, 256, 16, 48, 256, dt_proj_b, nullptr, nullptr, flag);

    // 6-8. selective scan
    scan_a_kernel<<<B_ * NCH * 16, blk, 0, stream>>>(delta, ub, xdbl, A_log, hend, dsum, flag);
    scan_b_kernel<<<64, blk, 0, stream>>>(A_log, hend, dsum, flag);
    scan_c_kernel<<<B_ * NCH * 16, blk, 0, stream>>>(delta, ub, xdbl, A_log, Dp, hend, yb, flag);

    // 9. out_proj + residual: [y | z] (M,512) x W(256,512)^T + x -> xres (bf16, overwrites u)
    gemm_kernel<EPI_RES, true, true><<<dim3(2, 98), blk, 0, stream>>>(
        yb, xnb, 256, out_proj_w, xres, 256, 512, 256, 256, nullptr, x, nullptr, flag);

    // 10. LN2: xres -> xn2 (bf16, overwrites z)
    ln_kernel<<<M_, blk, 0, stream>>>(xres, 1, ln2_g, ln2_b, xnb, flag);

    // 11. MLP1 + bias + GELU: xn2 x W(1024,256)^T -> hmid (bf16, overlays dead regions)
    gemm_kernel<EPI_GELU, true, true><<<dim3(8, 98), blk, 0, stream>>>(
        xnb, nullptr, 256, mlp_w1, hmid, 1024, 256, 256, 1024, mlp_b1, nullptr, nullptr, flag);

    // 12. MLP2 + bias + residual -> d_out (dtype per flag)
    gemm_kernel<EPI_OUT, true, true><<<dim3(2, 98), blk, 0, stream>>>(
        hmid, nullptr, 1024, mlp_w2, d_out, 256, 1024, 1024, 256, mlp_b2, nullptr, xres, flag);
}